// Round 4
// baseline (306.617 us; speedup 1.0000x reference)
//
#include <hip/hip_runtime.h>
#include <stdint.h>

#define B_ 2
#define T_ 2048
#define C_ 2048
#define NH 16
#define NG 4
#define HS 128

typedef unsigned short u16;
typedef __bf16 bf16_t;
typedef bf16_t bf16x8 __attribute__((ext_vector_type(8)));
typedef float f32x4 __attribute__((ext_vector_type(4)));

__device__ __forceinline__ u16 f2bf(float f) {
    union { float f; uint32_t u; } v; v.f = f;
    uint32_t r = (v.u + 0x7fffu + ((v.u >> 16) & 1u)) >> 16;
    return (u16)r;
}
__device__ __forceinline__ float fast_ex2(float x) {
    float r; asm("v_exp_f32 %0, %1" : "=v"(r) : "v"(x)); return r;
}

// ---------------- fused prep: x->bf16 convert + both weight transposes ----------------
__device__ __forceinline__ void transpose_body(const float* __restrict__ W, u16* __restrict__ Wt,
                                               int K, int N, int bx, int by, float (*tile)[33]) {
    int n0 = bx * 32, k0 = by * 32;
    int tx = threadIdx.x & 31, ty = threadIdx.x >> 5;
#pragma unroll
    for (int i = 0; i < 4; i++) {
        int r = ty + i * 8;
        tile[r][tx] = W[(size_t)(k0 + r) * N + (n0 + tx)];
    }
    __syncthreads();
#pragma unroll
    for (int i = 0; i < 4; i++) {
        int r = ty + i * 8;
        Wt[(size_t)(n0 + r) * K + (k0 + tx)] = f2bf(tile[tx][r]);
    }
}

__global__ void k_prep(const float* __restrict__ x, u16* __restrict__ xb,
                       const float* __restrict__ wa, u16* __restrict__ wat,
                       const float* __restrict__ wp, u16* __restrict__ wpt) {
    __shared__ float tile[32][33];
    int bid = blockIdx.x;
    if (bid < 8192) {
        int i = bid * 256 + threadIdx.x;
        float4 f = ((const float4*)x)[i];
        ushort4 o;
        o.x = f2bf(f.x); o.y = f2bf(f.y); o.z = f2bf(f.z); o.w = f2bf(f.w);
        ((ushort4*)xb)[i] = o;
    } else if (bid < 8192 + 6144) {
        int id = bid - 8192;
        transpose_body(wa, wat, 2048, 3072, id % 96, id / 96, tile);
    } else {
        int id = bid - 14336;
        transpose_body(wp, wpt, 2048, 2048, id % 64, id / 64, tile);
    }
}

// ---------------- shared 8-phase GEMM machinery (T2+T3+T4+T5) ----------------
#define MIDB { __builtin_amdgcn_s_barrier();                              \
               asm volatile("s_waitcnt lgkmcnt(0)" ::: "memory");         \
               __builtin_amdgcn_sched_barrier(0); }
#define ENDB { __builtin_amdgcn_s_barrier(); }
#define VMW4 { asm volatile("s_waitcnt vmcnt(4)" ::: "memory"); }
#define VMW0 { asm volatile("s_waitcnt vmcnt(0)" ::: "memory"); }

// stage 128 rows x 64 k (16 KB), 2 loads/thread, pre-swizzled source col
__device__ __forceinline__ void stage_half(const u16* __restrict__ g, int r0, int k0,
                                           u16* l, int tid) {
#pragma unroll
    for (int i = 0; i < 2; i++) {
        int c = tid + i * 512;
        int row = c >> 3, sl = c & 7;
        const u16* ga = g + (size_t)(r0 + row) * 2048 + k0 + (sl ^ (row & 7)) * 8;
        __builtin_amdgcn_global_load_lds((const __attribute__((address_space(1))) void*)ga,
                                         (__attribute__((address_space(3))) void*)(l + c * 8),
                                         16, 0, 0);
    }
}

// stage 64 rows x 64 k (8 KB), 1 load/thread
__device__ __forceinline__ void stage_half64(const u16* __restrict__ g, int r0, int k0,
                                             u16* l, int tid) {
    int row = tid >> 3, sl = tid & 7;
    const u16* ga = g + (size_t)(r0 + row) * 2048 + k0 + (sl ^ (row & 7)) * 8;
    __builtin_amdgcn_global_load_lds((const __attribute__((address_space(1))) void*)ga,
                                     (__attribute__((address_space(3))) void*)(l + tid * 8),
                                     16, 0, 0);
}

__device__ __forceinline__ void rd_a(const u16* slot, int mq, int l16, int quad,
                                     bf16x8 (&af)[4][2]) {
#pragma unroll
    for (int mf = 0; mf < 4; mf++) {
        int row = mq * 64 + mf * 16 + l16;
#pragma unroll
        for (int kk = 0; kk < 2; kk++)
            af[mf][kk] = *(const bf16x8*)(slot + row * 64 + ((kk * 4 + quad) ^ (l16 & 7)) * 8);
    }
}

// 2-fragment read: rows sub*64 + nq*32 + {0,16} + l16 (also used as 64-row A reader with sub=0)
__device__ __forceinline__ void rd_b(const u16* slot, int nq, int sub, int l16, int quad,
                                     bf16x8 (&bs)[2][2]) {
#pragma unroll
    for (int g = 0; g < 2; g++) {
        int row = sub * 64 + (nq * 2 + g) * 16 + l16;
#pragma unroll
        for (int kk = 0; kk < 2; kk++)
            bs[g][kk] = *(const bf16x8*)(slot + row * 64 + ((kk * 4 + quad) ^ (l16 & 7)) * 8);
    }
}

template <int MQ, int NQ>
__device__ __forceinline__ void mm8(f32x4 (&acc)[8][4], const bf16x8 (&af)[4][2],
                                    const bf16x8 (&bs)[2][2]) {
    __builtin_amdgcn_s_setprio(1);
#pragma unroll
    for (int mf = 0; mf < 4; mf++)
#pragma unroll
        for (int g = 0; g < 2; g++)
#pragma unroll
            for (int kk = 0; kk < 2; kk++)
                acc[MQ * 4 + mf][NQ * 2 + g] = __builtin_amdgcn_mfma_f32_16x16x32_bf16(
                    af[mf][kk], bs[g][kk], acc[MQ * 4 + mf][NQ * 2 + g], 0, 0, 0);
    __builtin_amdgcn_s_setprio(0);
}

template <int MQ, int NQ>
__device__ __forceinline__ void mm4(f32x4 (&acc)[4][4], const bf16x8 (&af)[2][2],
                                    const bf16x8 (&bs)[2][2]) {
    __builtin_amdgcn_s_setprio(1);
#pragma unroll
    for (int mf = 0; mf < 2; mf++)
#pragma unroll
        for (int g = 0; g < 2; g++)
#pragma unroll
            for (int kk = 0; kk < 2; kk++)
                acc[MQ * 2 + mf][NQ * 2 + g] = __builtin_amdgcn_mfma_f32_16x16x32_bf16(
                    af[mf][kk], bs[g][kk], acc[MQ * 2 + mf][NQ * 2 + g], 0, 0, 0);
    __builtin_amdgcn_s_setprio(0);
}

// ---------------- GEMM1: 256x256 8-phase, RoPE/pack epilogue ----------------
// XCD-chunked bijective block swizzle (T1/m204): 192 = 8 * 24.
__global__ __launch_bounds__(512, 2) void k_gemm_qkv(const u16* __restrict__ A,
                                                     const u16* __restrict__ Bt,
                                                     const float* __restrict__ cosb,
                                                     const float* __restrict__ sinb,
                                                     u16* __restrict__ qa,
                                                     u16* __restrict__ ka,
                                                     u16* __restrict__ vt) {
    extern __shared__ __align__(16) u16 sm[];
    const int tid = threadIdx.x;
    const int wave = tid >> 6, lane = tid & 63;
    const int quad = lane >> 4, l16 = lane & 15;
    const int wr = wave >> 2, wc = wave & 3;
    const int lin = blockIdx.x + 12 * blockIdx.y;
    const int swz = (lin & 7) * 24 + (lin >> 3);
    const int bx = swz % 12, by = swz / 12;
    const int m0 = by * 256;
    const int brow = bx * 256;

    const u16* As0 = sm + (0 * 2 + wr) * 8192;
    const u16* As1 = sm + (1 * 2 + wr) * 8192;
    const u16* Bs0 = sm + 32768 + (0 * 2 + (wc >> 1)) * 8192;
    const u16* Bs1 = sm + 32768 + (1 * 2 + (wc >> 1)) * 8192;

    f32x4 acc[8][4] = {};
    bf16x8 af[4][2], b0[2][2], b1[2][2];

    stage_half(A,  m0,        0,  sm + 0 * 8192, tid);
    stage_half(A,  m0 + 128,  0,  sm + 1 * 8192, tid);
    stage_half(Bt, brow,       0,  sm + 32768 + 0 * 8192, tid);
    stage_half(Bt, brow + 128, 0,  sm + 32768 + 1 * 8192, tid);
    stage_half(Bt, brow,       64, sm + 32768 + 2 * 8192, tid);
    stage_half(Bt, brow + 128, 64, sm + 32768 + 3 * 8192, tid);
    VMW4;
    __builtin_amdgcn_s_barrier();

    for (int i = 0; i < 15; i++) {
        const int k0 = i * 128;
        rd_a(As0, 0, l16, quad, af); rd_b(Bs0, 0, wc & 1, l16, quad, b0);
        stage_half(A, m0, k0 + 64, sm + 2 * 8192, tid);
        MIDB; mm8<0, 0>(acc, af, b0); ENDB;
        rd_b(Bs0, 1, wc & 1, l16, quad, b1);
        stage_half(A, m0 + 128, k0 + 64, sm + 3 * 8192, tid);
        MIDB; mm8<0, 1>(acc, af, b1); ENDB;
        rd_a(As0, 1, l16, quad, af);
        stage_half(Bt, brow, k0 + 128, sm + 32768 + 0 * 8192, tid);
        MIDB; mm8<1, 1>(acc, af, b1); ENDB;
        stage_half(Bt, brow + 128, k0 + 128, sm + 32768 + 1 * 8192, tid);
        MIDB; mm8<1, 0>(acc, af, b0); VMW4; ENDB;
        rd_a(As1, 0, l16, quad, af); rd_b(Bs1, 0, wc & 1, l16, quad, b0);
        stage_half(A, m0, k0 + 128, sm + 0 * 8192, tid);
        MIDB; mm8<0, 0>(acc, af, b0); ENDB;
        rd_b(Bs1, 1, wc & 1, l16, quad, b1);
        stage_half(A, m0 + 128, k0 + 128, sm + 1 * 8192, tid);
        MIDB; mm8<0, 1>(acc, af, b1); ENDB;
        rd_a(As1, 1, l16, quad, af);
        stage_half(Bt, brow, k0 + 192, sm + 32768 + 2 * 8192, tid);
        MIDB; mm8<1, 1>(acc, af, b1); ENDB;
        stage_half(Bt, brow + 128, k0 + 192, sm + 32768 + 3 * 8192, tid);
        MIDB; mm8<1, 0>(acc, af, b0); VMW4; ENDB;
    }
    {
        rd_a(As0, 0, l16, quad, af); rd_b(Bs0, 0, wc & 1, l16, quad, b0);
        stage_half(A, m0, 1984, sm + 2 * 8192, tid);
        MIDB; mm8<0, 0>(acc, af, b0); ENDB;
        rd_b(Bs0, 1, wc & 1, l16, quad, b1);
        stage_half(A, m0 + 128, 1984, sm + 3 * 8192, tid);
        MIDB; mm8<0, 1>(acc, af, b1); ENDB;
        rd_a(As0, 1, l16, quad, af);
        MIDB; mm8<1, 1>(acc, af, b1); ENDB;
        MIDB; mm8<1, 0>(acc, af, b0); VMW0; ENDB;
        rd_a(As1, 0, l16, quad, af); rd_b(Bs1, 0, wc & 1, l16, quad, b0);
        MIDB; mm8<0, 0>(acc, af, b0); ENDB;
        rd_b(Bs1, 1, wc & 1, l16, quad, b1);
        MIDB; mm8<0, 1>(acc, af, b1); ENDB;
        rd_a(As1, 1, l16, quad, af);
        MIDB; mm8<1, 1>(acc, af, b1); ENDB;
        MIDB; mm8<1, 0>(acc, af, b0); ENDB;
    }

    __syncthreads();
    const int s = bx * 2 + (wc >> 1);
    const int stype = s % 6, grp = s / 6;
    const int dhalf = wc & 1;
    const int b = by >> 3;
    const int tb = (by & 7) * 256 + wr * 128;
    const int rid = wr * 2 + (wc >> 1);
    float4* xch = (float4*)sm;

    if (stype < 5 && dhalf == 1) {
#pragma unroll
        for (int mf = 0; mf < 8; mf++)
#pragma unroll
            for (int g = 0; g < 4; g++)
                xch[((rid * 8 + mf) * 4 + g) * 64 + quad * 16 + l16] = *(float4*)&acc[mf][g];
    }
    __syncthreads();
    if (stype < 5) {
        if (dhalf == 0) {
            const float QS = 0.08838834764831845f * 1.44269504088896341f; // scale*log2e
            const float sc = (stype < 4) ? QS : 1.0f;
            u16* dst = (stype < 4) ? qa + ((size_t)(b * NH + grp * 4 + stype)) * T_ * 128
                                   : ka + ((size_t)(b * NG + grp)) * T_ * 128;
#pragma unroll
            for (int mf = 0; mf < 8; mf++)
#pragma unroll
                for (int g = 0; g < 4; g++) {
                    float4 x2 = xch[((rid * 8 + mf) * 4 + g) * 64 + quad * 16 + l16];
                    const float* x2p = (const float*)&x2;
                    int d = g * 16 + l16;
#pragma unroll
                    for (int r = 0; r < 4; r++) {
                        int t = tb + mf * 16 + quad * 4 + r;
                        float cc = cosb[t * 64 + d], ss = sinb[t * 64 + d];
                        float x1 = acc[mf][g][r];
                        u16* drow = dst + (size_t)t * 128;
                        drow[d] = f2bf((x1 * cc - x2p[r] * ss) * sc);
                        drow[d + 64] = f2bf((x1 * ss + x2p[r] * cc) * sc);
                    }
                }
        }
    } else {
        size_t vb = ((size_t)(b * NG + grp)) * 128;
#pragma unroll
        for (int mf = 0; mf < 8; mf++)
#pragma unroll
            for (int g = 0; g < 4; g++) {
                int d = dhalf * 64 + g * 16 + l16;
                int t0 = tb + mf * 16 + quad * 4;
                ushort4 o = make_ushort4(f2bf(acc[mf][g][0]), f2bf(acc[mf][g][1]),
                                         f2bf(acc[mf][g][2]), f2bf(acc[mf][g][3]));
                *(ushort4*)(vt + (vb + d) * T_ + t0) = o;
            }
    }
}

// ---------------- GEMM2: out = ya @ w_proj^T, 8-phase BM=128/BN=256, fp32 out ----------------
// XCD-chunked bijective block swizzle: 256 = 8 * 32.
__global__ __launch_bounds__(512, 2) void k_gemm_bt(const u16* __restrict__ A,
                                                    const u16* __restrict__ Bt,
                                                    float* __restrict__ C) {
    extern __shared__ __align__(16) u16 sm[];
    const int tid = threadIdx.x;
    const int wave = tid >> 6, lane = tid & 63;
    const int quad = lane >> 4, l16 = lane & 15;
    const int wr = wave >> 2, wc = wave & 3;
    const int bh = wc >> 1, sub = wc & 1;
    const int lin = blockIdx.x + 8 * blockIdx.y;
    const int swz = (lin & 7) * 32 + (lin >> 3);
    const int bx = swz & 7, by = swz >> 3;
    const int m0 = by * 128, n0 = bx * 256;

    const u16* As0 = sm + (0 * 2 + wr) * 4096;
    const u16* As1 = sm + (1 * 2 + wr) * 4096;
    const u16* Bs0 = sm + 16384 + (0 * 2 + bh) * 8192;
    const u16* Bs1 = sm + 16384 + (1 * 2 + bh) * 8192;

    f32x4 acc[4][4] = {};
    bf16x8 af[2][2], b0[2][2], b1[2][2];

    stage_half64(A, m0,       0, sm + 0 * 4096, tid);
    stage_half64(A, m0 + 64,  0, sm + 1 * 4096, tid);
    stage_half(Bt, n0,        0, sm + 16384 + 0 * 8192, tid);
    stage_half(Bt, n0 + 128,  0, sm + 16384 + 1 * 8192, tid);
    stage_half(Bt, n0,       64, sm + 16384 + 2 * 8192, tid);
    stage_half(Bt, n0 + 128, 64, sm + 16384 + 3 * 8192, tid);
    VMW4;
    __builtin_amdgcn_s_barrier();

    for (int i = 0; i < 15; i++) {
        const int k0 = i * 128;
        rd_b(As0, 0, 0, l16, quad, af); rd_b(Bs0, 0, sub, l16, quad, b0);
        stage_half64(A, m0, k0 + 64, sm + 2 * 4096, tid);
        MIDB; mm4<0, 0>(acc, af, b0); ENDB;
        rd_b(Bs0, 1, sub, l16, quad, b1);
        stage_half64(A, m0 + 64, k0 + 64, sm + 3 * 4096, tid);
        MIDB; mm4<0, 1>(acc, af, b1); ENDB;
        rd_b(As0, 1, 0, l16, quad, af);
        stage_half(Bt, n0, k0 + 128, sm + 16384 + 0 * 8192, tid);
        MIDB; mm4<1, 1>(acc, af, b1); ENDB;
        stage_half(Bt, n0 + 128, k0 + 128, sm + 16384 + 1 * 8192, tid);
        MIDB; mm4<1, 0>(acc, af, b0); VMW4; ENDB;
        rd_b(As1, 0, 0, l16, quad, af); rd_b(Bs1, 0, sub, l16, quad, b0);
        stage_half64(A, m0, k0 + 128, sm + 0 * 4096, tid);
        MIDB; mm4<0, 0>(acc, af, b0); ENDB;
        rd_b(Bs1, 1, sub, l16, quad, b1);
        stage_half64(A, m0 + 64, k0 + 128, sm + 1 * 4096, tid);
        MIDB; mm4<0, 1>(acc, af, b1); ENDB;
        rd_b(As1, 1, 0, l16, quad, af);
        stage_half(Bt, n0, k0 + 192, sm + 16384 + 2 * 8192, tid);
        MIDB; mm4<1, 1>(acc, af, b1); ENDB;
        stage_half(Bt, n0 + 128, k0 + 192, sm + 16384 + 3 * 8192, tid);
        MIDB; mm4<1, 0>(acc, af, b0); VMW4; ENDB;
    }
    {
        rd_b(As0, 0, 0, l16, quad, af); rd_b(Bs0, 0, sub, l16, quad, b0);
        stage_half64(A, m0, 1984, sm + 2 * 4096, tid);
        MIDB; mm4<0, 0>(acc, af, b0); ENDB;
        rd_b(Bs0, 1, sub, l16, quad, b1);
        stage_half64(A, m0 + 64, 1984, sm + 3 * 4096, tid);
        MIDB; mm4<0, 1>(acc, af, b1); ENDB;
        rd_b(As0, 1, 0, l16, quad, af);
        MIDB; mm4<1, 1>(acc, af, b1); ENDB;
        MIDB; mm4<1, 0>(acc, af, b0); VMW0; ENDB;
        rd_b(As1, 0, 0, l16, quad, af); rd_b(Bs1, 0, sub, l16, quad, b0);
        MIDB; mm4<0, 0>(acc, af, b0); ENDB;
        rd_b(Bs1, 1, sub, l16, quad, b1);
        MIDB; mm4<0, 1>(acc, af, b1); ENDB;
        rd_b(As1, 1, 0, l16, quad, af);
        MIDB; mm4<1, 1>(acc, af, b1); ENDB;
        MIDB; mm4<1, 0>(acc, af, b0); ENDB;
    }

#pragma unroll
    for (int am = 0; am < 4; am++)
#pragma unroll
        for (int an = 0; an < 4; an++)
#pragma unroll
            for (int r = 0; r < 4; r++) {
                int row = m0 + wr * 64 + am * 16 + quad * 4 + r;
                int col = n0 + wc * 64 + an * 16 + l16;
                C[(size_t)row * C_ + col] = acc[am][an][r];
            }
}

// ---------------- flash attention: deferred-PV pipeline (T15) ----------------
// 128 q/block (4 waves x 32 q), 64-key tiles, 2 blocks/CU, 80 KB dyn LDS:
//   Ks[2] (16KB each) @ u16 {0, 8192}; Vs[3] @ {16384, 24576, 32768}.
// Iter t: issue K(t+1) gload_lds + V(t+1)->regs; QK(t); softmax(t)->pkNew;
//         PV(t-1) with pkOld  [MFMA/LDS overlaps softmax VALU - independent];
//         vmcnt(0); V-write(t+1)->Vs[(t+1)%3]; barrier.
// V needs 3 buffers: read t-1 now, read t next iter, write t+1 now.
__global__ __launch_bounds__(256, 2) void k_attn(const u16* __restrict__ qa,
                                                 const u16* __restrict__ ka,
                                                 const u16* __restrict__ vt,
                                                 u16* __restrict__ ya) {
    extern __shared__ __align__(16) u16 smem[]; // 80 KB
    u16* Ks = smem;
    u16* Vs = smem + 16384;
    const int tid = threadIdx.x;
    const int wave = tid >> 6, lane = tid & 63;
    const int quad = lane >> 4, l16 = lane & 15;
    const int qt = blockIdx.x, h = blockIdx.y, b = blockIdx.z;
    const int g = h >> 2;

    bf16x8 qf[2][4];
    {
        const u16* qbase = qa + (((size_t)(b * NH + h)) * T_ + qt * 128 + wave * 32 + l16) * 128;
#pragma unroll
        for (int t16 = 0; t16 < 2; t16++)
#pragma unroll
            for (int ks = 0; ks < 4; ks++)
                qf[t16][ks] = *(const bf16x8*)(qbase + t16 * 16 * 128 + ks * 32 + quad * 8);
    }
    const u16* kbase = ka + ((size_t)(b * NG + g)) * T_ * 128;
    const u16* vbase = vt + ((size_t)(b * NG + g)) * 128 * T_;

    // hoisted per-thread staging offsets (loop-invariant)
    int kdst[4], ksrc[4], vsrc[4], vdA[4], vdB[4];
#pragma unroll
    for (int i = 0; i < 4; i++) {
        int c = tid + i * 256;
        int row = c >> 4, seg = c & 15;
        kdst[i] = c * 8;
        ksrc[i] = row * 128 + (seg ^ (row & 15)) * 8;
        int d = c >> 3, m = c & 7;
        vsrc[i] = d * T_ + m * 8;
        int segA = (m >> 2) * 4 + (m & 1) * 2;
        int a4 = ((m >> 1) & 1) * 4;
        vdA[i] = d * 64 + (segA ^ (d & 7)) * 8 + a4;
        vdB[i] = d * 64 + ((segA + 1) ^ (d & 7)) * 8 + a4;
    }

    f32x4 yacc[2][8] = {};
    float lsum[2] = {0.f, 0.f};
    uint4 vr[4];
    uint32_t pkA[2][4][2], pkB[2][4][2];
    f32x4 sacc[2][4];

    auto ISSUE_K = [&](int kt) {
        u16* Kn = Ks + (kt & 1) * 8192;
        const u16* kb = kbase + (size_t)kt * 8192;
#pragma unroll
        for (int i = 0; i < 4; i++)
            __builtin_amdgcn_global_load_lds(
                (const __attribute__((address_space(1))) void*)(kb + ksrc[i]),
                (__attribute__((address_space(3))) void*)(Kn + kdst[i]), 16, 0, 0);
    };
    auto LOAD_V = [&](int kt) {
        const u16* vb = vbase + kt * 64;
#pragma unroll
        for (int i = 0; i < 4; i++) vr[i] = *(const uint4*)(vb + vsrc[i]);
    };
    auto WRITE_V = [&](int kt) {
        u16* Vc = Vs + (kt % 3) * 8192;
#pragma unroll
        for (int i = 0; i < 4; i++) {
            *(uint2*)&Vc[vdA[i]] = make_uint2(vr[i].x, vr[i].y);
            *(uint2*)&Vc[vdB[i]] = make_uint2(vr[i].z, vr[i].w);
        }
    };
    auto QK = [&](int kt) {
        const u16* Kc = Ks + (kt & 1) * 8192;
#pragma unroll
        for (int t16 = 0; t16 < 2; t16++)
#pragma unroll
            for (int ni = 0; ni < 4; ni++) sacc[t16][ni] = f32x4{0.f, 0.f, 0.f, 0.f};
        __builtin_amdgcn_s_setprio(1);
#pragma unroll
        for (int ks = 0; ks < 4; ks++) {
#pragma unroll
            for (int ni = 0; ni < 4; ni++) {
                bf16x8 kf = *(const bf16x8*)&Kc[(ni * 16 + l16) * 128 + ((ks * 4 + quad) ^ l16) * 8];
                sacc[0][ni] = __builtin_amdgcn_mfma_f32_16x16x32_bf16(kf, qf[0][ks], sacc[0][ni], 0, 0, 0);
                sacc[1][ni] = __builtin_amdgcn_mfma_f32_16x16x32_bf16(kf, qf[1][ks], sacc[1][ni], 0, 0, 0);
            }
        }
        __builtin_amdgcn_s_setprio(0);
    };
    auto SM = [&](uint32_t (&pk)[2][4][2]) {
#pragma unroll
        for (int t16 = 0; t16 < 2; t16++) {
#pragma unroll
            for (int ni = 0; ni < 4; ni++) {
                float p0 = fast_ex2(sacc[t16][ni][0]);
                float p1 = fast_ex2(sacc[t16][ni][1]);
                float p2 = fast_ex2(sacc[t16][ni][2]);
                float p3 = fast_ex2(sacc[t16][ni][3]);
                lsum[t16] += (p0 + p1) + (p2 + p3);
                asm("v_cvt_pk_bf16_f32 %0, %1, %2" : "=v"(pk[t16][ni][0]) : "v"(p0), "v"(p1));
                asm("v_cvt_pk_bf16_f32 %0, %1, %2" : "=v"(pk[t16][ni][1]) : "v"(p2), "v"(p3));
            }
        }
    };
    auto PV = [&](int kt, uint32_t (&pk)[2][4][2]) {
        const u16* Vc = Vs + (kt % 3) * 8192;
        __builtin_amdgcn_s_setprio(1);
#pragma unroll
        for (int ks2 = 0; ks2 < 2; ks2++) {
            union { uint32_t u[4]; bf16x8 v; } pf0, pf1;
            pf0.u[0] = pk[0][2 * ks2][0];     pf0.u[1] = pk[0][2 * ks2][1];
            pf0.u[2] = pk[0][2 * ks2 + 1][0]; pf0.u[3] = pk[0][2 * ks2 + 1][1];
            pf1.u[0] = pk[1][2 * ks2][0];     pf1.u[1] = pk[1][2 * ks2][1];
            pf1.u[2] = pk[1][2 * ks2 + 1][0]; pf1.u[3] = pk[1][2 * ks2 + 1][1];
#pragma unroll
            for (int tile = 0; tile < 8; tile++) {
                bf16x8 vf = *(const bf16x8*)&Vc[(tile * 16 + l16) * 64 +
                                                ((ks2 * 4 + quad) ^ (l16 & 7)) * 8];
                yacc[0][tile] = __builtin_amdgcn_mfma_f32_16x16x32_bf16(vf, pf0.v, yacc[0][tile], 0, 0, 0);
                yacc[1][tile] = __builtin_amdgcn_mfma_f32_16x16x32_bf16(vf, pf1.v, yacc[1][tile], 0, 0, 0);
            }
        }
        __builtin_amdgcn_s_setprio(0);
    };

    // prologue: land K(0), V(0)
    ISSUE_K(0); LOAD_V(0);
    VMW0; WRITE_V(0); __syncthreads();
    // iter 0 (no PV)
    ISSUE_K(1); LOAD_V(1);
    QK(0); SM(pkA);
    VMW0; WRITE_V(1); __syncthreads();
    // main pairs: t = kt (X, pkA->PV, SM->pkB) and t = kt+1 (Y, pkB->PV, SM->pkA)
    for (int kt = 1; kt <= 29; kt += 2) {
        ISSUE_K(kt + 1); LOAD_V(kt + 1);
        QK(kt); SM(pkB); PV(kt - 1, pkA);
        VMW0; WRITE_V(kt + 1); __syncthreads();
        ISSUE_K(kt + 2); LOAD_V(kt + 2);
        QK(kt + 1); SM(pkA); PV(kt, pkB);
        VMW0; WRITE_V(kt + 2); __syncthreads();
    }
    // iter 31 (no staging) + drain
    QK(31); SM(pkB); PV(30, pkA);
    PV(31, pkB);

    // reduce l across the 4 lane-replicas (lanes 16/32 apart hold same q)
#pragma unroll
    for (int t16 = 0; t16 < 2; t16++) {
        lsum[t16] += __shfl_xor(lsum[t16], 16);
        lsum[t16] += __shfl_xor(lsum[t16], 32);
    }

    // epilogue: Y^T[d][q] registers -> LDS [q][d] (swizzled) -> coalesced global
    __syncthreads();
#pragma unroll
    for (int t16 = 0; t16 < 2; t16++) {
        float inv = 1.f / lsum[t16];
        int qrow = wave * 32 + t16 * 16 + l16;
#pragma unroll
        for (int tile = 0; tile < 8; tile++) {
#pragma unroll
            for (int cp = 0; cp < 2; cp++) {
                int d = tile * 16 + quad * 4 + cp * 2;
                uint32_t pv = (uint32_t)f2bf(yacc[t16][tile][cp * 2] * inv) |
                              ((uint32_t)f2bf(yacc[t16][tile][cp * 2 + 1] * inv) << 16);
                *(uint32_t*)&smem[qrow * 128 + ((d >> 3) ^ l16) * 8 + (d & 7)] = pv;
            }
        }
    }
    __syncthreads();
#pragma unroll
    for (int i = 0; i < 8; i++) {
        int cc = tid + i * 256;
        int row = cc >> 4, seg = cc & 15;
        uint4 dv = *(const uint4*)&smem[row * 128 + (seg ^ (row & 15)) * 8];
        size_t q = (size_t)(b * T_ + qt * 128 + row);
        *(uint4*)(ya + q * C_ + h * 128 + seg * 8) = dv;
    }
}

extern "C" void kernel_launch(void* const* d_in, const int* in_sizes, int n_in,
                              void* d_out, int out_size, void* d_ws, size_t ws_size,
                              hipStream_t stream) {
    (void)in_sizes; (void)n_in; (void)out_size; (void)ws_size;
    const float* x = (const float*)d_in[0];
    const float* cosb = (const float*)d_in[1];
    const float* sinb = (const float*)d_in[2];
    const float* w_attn = (const float*)d_in[3];
    const float* w_proj = (const float*)d_in[4];
    float* out = (float*)d_out;

    char* ws = (char*)d_ws;
    size_t off = 0;
    auto alloc = [&](size_t bytes) -> char* {
        char* p = ws + off;
        off += (bytes + 255) & ~(size_t)255;
        return p;
    };
    u16* xb  = (u16*)alloc((size_t)4096 * 2048 * 2);
    u16* wat = (u16*)alloc((size_t)3072 * 2048 * 2);
    u16* wpt = (u16*)alloc((size_t)2048 * 2048 * 2);
    u16* qa  = (u16*)alloc((size_t)B_ * NH * T_ * HS * 2);
    u16* ka  = (u16*)alloc((size_t)B_ * NG * T_ * HS * 2);
    u16* vt  = (u16*)alloc((size_t)B_ * NG * T_ * HS * 2);
    u16* ya  = xb; // xb dead after gemm1

    static bool smset = false;
    if (!smset) {
        (void)hipFuncSetAttribute((const void*)k_gemm_qkv,
                                  hipFuncAttributeMaxDynamicSharedMemorySize, 131072);
        (void)hipFuncSetAttribute((const void*)k_gemm_bt,
                                  hipFuncAttributeMaxDynamicSharedMemorySize, 98304);
        (void)hipFuncSetAttribute((const void*)k_attn,
                                  hipFuncAttributeMaxDynamicSharedMemorySize, 81920);
        smset = true;
    }

    k_prep<<<dim3(18432), dim3(256), 0, stream>>>(x, xb, w_attn, wat, w_proj, wpt);
    k_gemm_qkv<<<dim3(12, 16), dim3(512), 131072, stream>>>(xb, wat, cosb, sinb, qa, ka, vt);
    k_attn<<<dim3(16, 16, 2), dim3(256), 81920, stream>>>(qa, ka, vt, ya);
    k_gemm_bt<<<dim3(8, 32), dim3(512), 98304, stream>>>(ya, wpt, out);
}

// Round 5
// 274.684 us; speedup vs baseline: 1.1163x; 1.1163x over previous
//
#include <hip/hip_runtime.h>
#include <stdint.h>

#define B_ 2
#define T_ 2048
#define C_ 2048
#define NH 16
#define NG 4
#define HS 128

typedef unsigned short u16;
typedef __bf16 bf16_t;
typedef bf16_t bf16x8 __attribute__((ext_vector_type(8)));
typedef float f32x4 __attribute__((ext_vector_type(4)));

__device__ __forceinline__ u16 f2bf(float f) {
    union { float f; uint32_t u; } v; v.f = f;
    uint32_t r = (v.u + 0x7fffu + ((v.u >> 16) & 1u)) >> 16;
    return (u16)r;
}
__device__ __forceinline__ float fast_ex2(float x) {
    float r; asm("v_exp_f32 %0, %1" : "=v"(r) : "v"(x)); return r;
}

// ---------------- fused prep: x->bf16 convert + both weight transposes ----------------
__device__ __forceinline__ void transpose_body(const float* __restrict__ W, u16* __restrict__ Wt,
                                               int K, int N, int bx, int by, float (*tile)[33]) {
    int n0 = bx * 32, k0 = by * 32;
    int tx = threadIdx.x & 31, ty = threadIdx.x >> 5;
#pragma unroll
    for (int i = 0; i < 4; i++) {
        int r = ty + i * 8;
        tile[r][tx] = W[(size_t)(k0 + r) * N + (n0 + tx)];
    }
    __syncthreads();
#pragma unroll
    for (int i = 0; i < 4; i++) {
        int r = ty + i * 8;
        Wt[(size_t)(n0 + r) * K + (k0 + tx)] = f2bf(tile[tx][r]);
    }
}

__global__ void k_prep(const float* __restrict__ x, u16* __restrict__ xb,
                       const float* __restrict__ wa, u16* __restrict__ wat,
                       const float* __restrict__ wp, u16* __restrict__ wpt) {
    __shared__ float tile[32][33];
    int bid = blockIdx.x;
    if (bid < 8192) {
        int i = bid * 256 + threadIdx.x;
        float4 f = ((const float4*)x)[i];
        ushort4 o;
        o.x = f2bf(f.x); o.y = f2bf(f.y); o.z = f2bf(f.z); o.w = f2bf(f.w);
        ((ushort4*)xb)[i] = o;
    } else if (bid < 8192 + 6144) {
        int id = bid - 8192;
        transpose_body(wa, wat, 2048, 3072, id % 96, id / 96, tile);
    } else {
        int id = bid - 14336;
        transpose_body(wp, wpt, 2048, 2048, id % 64, id / 64, tile);
    }
}

// ---------------- shared 8-phase GEMM machinery (T2+T3+T4+T5) ----------------
#define MIDB { __builtin_amdgcn_s_barrier();                              \
               asm volatile("s_waitcnt lgkmcnt(0)" ::: "memory");         \
               __builtin_amdgcn_sched_barrier(0); }
#define ENDB { __builtin_amdgcn_s_barrier(); }
#define VMW4 { asm volatile("s_waitcnt vmcnt(4)" ::: "memory"); }
#define VMW0 { asm volatile("s_waitcnt vmcnt(0)" ::: "memory"); }

// stage 128 rows x 64 k (16 KB), 2 loads/thread, pre-swizzled source col
__device__ __forceinline__ void stage_half(const u16* __restrict__ g, int r0, int k0,
                                           u16* l, int tid) {
#pragma unroll
    for (int i = 0; i < 2; i++) {
        int c = tid + i * 512;
        int row = c >> 3, sl = c & 7;
        const u16* ga = g + (size_t)(r0 + row) * 2048 + k0 + (sl ^ (row & 7)) * 8;
        __builtin_amdgcn_global_load_lds((const __attribute__((address_space(1))) void*)ga,
                                         (__attribute__((address_space(3))) void*)(l + c * 8),
                                         16, 0, 0);
    }
}

// stage 64 rows x 64 k (8 KB), 1 load/thread
__device__ __forceinline__ void stage_half64(const u16* __restrict__ g, int r0, int k0,
                                             u16* l, int tid) {
    int row = tid >> 3, sl = tid & 7;
    const u16* ga = g + (size_t)(r0 + row) * 2048 + k0 + (sl ^ (row & 7)) * 8;
    __builtin_amdgcn_global_load_lds((const __attribute__((address_space(1))) void*)ga,
                                     (__attribute__((address_space(3))) void*)(l + tid * 8),
                                     16, 0, 0);
}

__device__ __forceinline__ void rd_a(const u16* slot, int mq, int l16, int quad,
                                     bf16x8 (&af)[4][2]) {
#pragma unroll
    for (int mf = 0; mf < 4; mf++) {
        int row = mq * 64 + mf * 16 + l16;
#pragma unroll
        for (int kk = 0; kk < 2; kk++)
            af[mf][kk] = *(const bf16x8*)(slot + row * 64 + ((kk * 4 + quad) ^ (l16 & 7)) * 8);
    }
}

// 2-fragment read: rows sub*64 + nq*32 + {0,16} + l16 (also used as 64-row A reader with sub=0)
__device__ __forceinline__ void rd_b(const u16* slot, int nq, int sub, int l16, int quad,
                                     bf16x8 (&bs)[2][2]) {
#pragma unroll
    for (int g = 0; g < 2; g++) {
        int row = sub * 64 + (nq * 2 + g) * 16 + l16;
#pragma unroll
        for (int kk = 0; kk < 2; kk++)
            bs[g][kk] = *(const bf16x8*)(slot + row * 64 + ((kk * 4 + quad) ^ (l16 & 7)) * 8);
    }
}

template <int MQ, int NQ>
__device__ __forceinline__ void mm8(f32x4 (&acc)[8][4], const bf16x8 (&af)[4][2],
                                    const bf16x8 (&bs)[2][2]) {
    __builtin_amdgcn_s_setprio(1);
#pragma unroll
    for (int mf = 0; mf < 4; mf++)
#pragma unroll
        for (int g = 0; g < 2; g++)
#pragma unroll
            for (int kk = 0; kk < 2; kk++)
                acc[MQ * 4 + mf][NQ * 2 + g] = __builtin_amdgcn_mfma_f32_16x16x32_bf16(
                    af[mf][kk], bs[g][kk], acc[MQ * 4 + mf][NQ * 2 + g], 0, 0, 0);
    __builtin_amdgcn_s_setprio(0);
}

template <int MQ, int NQ>
__device__ __forceinline__ void mm4(f32x4 (&acc)[4][4], const bf16x8 (&af)[2][2],
                                    const bf16x8 (&bs)[2][2]) {
    __builtin_amdgcn_s_setprio(1);
#pragma unroll
    for (int mf = 0; mf < 2; mf++)
#pragma unroll
        for (int g = 0; g < 2; g++)
#pragma unroll
            for (int kk = 0; kk < 2; kk++)
                acc[MQ * 2 + mf][NQ * 2 + g] = __builtin_amdgcn_mfma_f32_16x16x32_bf16(
                    af[mf][kk], bs[g][kk], acc[MQ * 2 + mf][NQ * 2 + g], 0, 0, 0);
    __builtin_amdgcn_s_setprio(0);
}

// ---------------- GEMM1: 256x256 8-phase, RoPE/pack epilogue ----------------
// XCD-chunked bijective block swizzle (T1/m204): 192 = 8 * 24.
__global__ __launch_bounds__(512, 2) void k_gemm_qkv(const u16* __restrict__ A,
                                                     const u16* __restrict__ Bt,
                                                     const float* __restrict__ cosb,
                                                     const float* __restrict__ sinb,
                                                     u16* __restrict__ qa,
                                                     u16* __restrict__ ka,
                                                     u16* __restrict__ vt) {
    extern __shared__ __align__(16) u16 sm[];
    const int tid = threadIdx.x;
    const int wave = tid >> 6, lane = tid & 63;
    const int quad = lane >> 4, l16 = lane & 15;
    const int wr = wave >> 2, wc = wave & 3;
    const int lin = blockIdx.x + 12 * blockIdx.y;
    const int swz = (lin & 7) * 24 + (lin >> 3);
    const int bx = swz % 12, by = swz / 12;
    const int m0 = by * 256;
    const int brow = bx * 256;

    const u16* As0 = sm + (0 * 2 + wr) * 8192;
    const u16* As1 = sm + (1 * 2 + wr) * 8192;
    const u16* Bs0 = sm + 32768 + (0 * 2 + (wc >> 1)) * 8192;
    const u16* Bs1 = sm + 32768 + (1 * 2 + (wc >> 1)) * 8192;

    f32x4 acc[8][4] = {};
    bf16x8 af[4][2], b0[2][2], b1[2][2];

    stage_half(A,  m0,        0,  sm + 0 * 8192, tid);
    stage_half(A,  m0 + 128,  0,  sm + 1 * 8192, tid);
    stage_half(Bt, brow,       0,  sm + 32768 + 0 * 8192, tid);
    stage_half(Bt, brow + 128, 0,  sm + 32768 + 1 * 8192, tid);
    stage_half(Bt, brow,       64, sm + 32768 + 2 * 8192, tid);
    stage_half(Bt, brow + 128, 64, sm + 32768 + 3 * 8192, tid);
    VMW4;
    __builtin_amdgcn_s_barrier();

    for (int i = 0; i < 15; i++) {
        const int k0 = i * 128;
        rd_a(As0, 0, l16, quad, af); rd_b(Bs0, 0, wc & 1, l16, quad, b0);
        stage_half(A, m0, k0 + 64, sm + 2 * 8192, tid);
        MIDB; mm8<0, 0>(acc, af, b0); ENDB;
        rd_b(Bs0, 1, wc & 1, l16, quad, b1);
        stage_half(A, m0 + 128, k0 + 64, sm + 3 * 8192, tid);
        MIDB; mm8<0, 1>(acc, af, b1); ENDB;
        rd_a(As0, 1, l16, quad, af);
        stage_half(Bt, brow, k0 + 128, sm + 32768 + 0 * 8192, tid);
        MIDB; mm8<1, 1>(acc, af, b1); ENDB;
        stage_half(Bt, brow + 128, k0 + 128, sm + 32768 + 1 * 8192, tid);
        MIDB; mm8<1, 0>(acc, af, b0); VMW4; ENDB;
        rd_a(As1, 0, l16, quad, af); rd_b(Bs1, 0, wc & 1, l16, quad, b0);
        stage_half(A, m0, k0 + 128, sm + 0 * 8192, tid);
        MIDB; mm8<0, 0>(acc, af, b0); ENDB;
        rd_b(Bs1, 1, wc & 1, l16, quad, b1);
        stage_half(A, m0 + 128, k0 + 128, sm + 1 * 8192, tid);
        MIDB; mm8<0, 1>(acc, af, b1); ENDB;
        rd_a(As1, 1, l16, quad, af);
        stage_half(Bt, brow, k0 + 192, sm + 32768 + 2 * 8192, tid);
        MIDB; mm8<1, 1>(acc, af, b1); ENDB;
        stage_half(Bt, brow + 128, k0 + 192, sm + 32768 + 3 * 8192, tid);
        MIDB; mm8<1, 0>(acc, af, b0); VMW4; ENDB;
    }
    {
        rd_a(As0, 0, l16, quad, af); rd_b(Bs0, 0, wc & 1, l16, quad, b0);
        stage_half(A, m0, 1984, sm + 2 * 8192, tid);
        MIDB; mm8<0, 0>(acc, af, b0); ENDB;
        rd_b(Bs0, 1, wc & 1, l16, quad, b1);
        stage_half(A, m0 + 128, 1984, sm + 3 * 8192, tid);
        MIDB; mm8<0, 1>(acc, af, b1); ENDB;
        rd_a(As0, 1, l16, quad, af);
        MIDB; mm8<1, 1>(acc, af, b1); ENDB;
        MIDB; mm8<1, 0>(acc, af, b0); VMW0; ENDB;
        rd_a(As1, 0, l16, quad, af); rd_b(Bs1, 0, wc & 1, l16, quad, b0);
        MIDB; mm8<0, 0>(acc, af, b0); ENDB;
        rd_b(Bs1, 1, wc & 1, l16, quad, b1);
        MIDB; mm8<0, 1>(acc, af, b1); ENDB;
        rd_a(As1, 1, l16, quad, af);
        MIDB; mm8<1, 1>(acc, af, b1); ENDB;
        MIDB; mm8<1, 0>(acc, af, b0); ENDB;
    }

    __syncthreads();
    const int s = bx * 2 + (wc >> 1);
    const int stype = s % 6, grp = s / 6;
    const int dhalf = wc & 1;
    const int b = by >> 3;
    const int tb = (by & 7) * 256 + wr * 128;
    const int rid = wr * 2 + (wc >> 1);
    float4* xch = (float4*)sm;

    if (stype < 5 && dhalf == 1) {
#pragma unroll
        for (int mf = 0; mf < 8; mf++)
#pragma unroll
            for (int g = 0; g < 4; g++)
                xch[((rid * 8 + mf) * 4 + g) * 64 + quad * 16 + l16] = *(float4*)&acc[mf][g];
    }
    __syncthreads();
    if (stype < 5) {
        if (dhalf == 0) {
            const float QS = 0.08838834764831845f * 1.44269504088896341f; // scale*log2e
            const float sc = (stype < 4) ? QS : 1.0f;
            u16* dst = (stype < 4) ? qa + ((size_t)(b * NH + grp * 4 + stype)) * T_ * 128
                                   : ka + ((size_t)(b * NG + grp)) * T_ * 128;
#pragma unroll
            for (int mf = 0; mf < 8; mf++)
#pragma unroll
                for (int g = 0; g < 4; g++) {
                    float4 x2 = xch[((rid * 8 + mf) * 4 + g) * 64 + quad * 16 + l16];
                    const float* x2p = (const float*)&x2;
                    int d = g * 16 + l16;
#pragma unroll
                    for (int r = 0; r < 4; r++) {
                        int t = tb + mf * 16 + quad * 4 + r;
                        float cc = cosb[t * 64 + d], ss = sinb[t * 64 + d];
                        float x1 = acc[mf][g][r];
                        u16* drow = dst + (size_t)t * 128;
                        drow[d] = f2bf((x1 * cc - x2p[r] * ss) * sc);
                        drow[d + 64] = f2bf((x1 * ss + x2p[r] * cc) * sc);
                    }
                }
        }
    } else {
        size_t vb = ((size_t)(b * NG + grp)) * 128;
#pragma unroll
        for (int mf = 0; mf < 8; mf++)
#pragma unroll
            for (int g = 0; g < 4; g++) {
                int d = dhalf * 64 + g * 16 + l16;
                int t0 = tb + mf * 16 + quad * 4;
                ushort4 o = make_ushort4(f2bf(acc[mf][g][0]), f2bf(acc[mf][g][1]),
                                         f2bf(acc[mf][g][2]), f2bf(acc[mf][g][3]));
                *(ushort4*)(vt + (vb + d) * T_ + t0) = o;
            }
    }
}

// ---------------- GEMM2: out = ya @ w_proj^T, 8-phase BM=128/BN=256, fp32 out ----------------
// XCD-chunked bijective block swizzle: 256 = 8 * 32.
__global__ __launch_bounds__(512, 2) void k_gemm_bt(const u16* __restrict__ A,
                                                    const u16* __restrict__ Bt,
                                                    float* __restrict__ C) {
    extern __shared__ __align__(16) u16 sm[];
    const int tid = threadIdx.x;
    const int wave = tid >> 6, lane = tid & 63;
    const int quad = lane >> 4, l16 = lane & 15;
    const int wr = wave >> 2, wc = wave & 3;
    const int bh = wc >> 1, sub = wc & 1;
    const int lin = blockIdx.x + 8 * blockIdx.y;
    const int swz = (lin & 7) * 32 + (lin >> 3);
    const int bx = swz & 7, by = swz >> 3;
    const int m0 = by * 128, n0 = bx * 256;

    const u16* As0 = sm + (0 * 2 + wr) * 4096;
    const u16* As1 = sm + (1 * 2 + wr) * 4096;
    const u16* Bs0 = sm + 16384 + (0 * 2 + bh) * 8192;
    const u16* Bs1 = sm + 16384 + (1 * 2 + bh) * 8192;

    f32x4 acc[4][4] = {};
    bf16x8 af[2][2], b0[2][2], b1[2][2];

    stage_half64(A, m0,       0, sm + 0 * 4096, tid);
    stage_half64(A, m0 + 64,  0, sm + 1 * 4096, tid);
    stage_half(Bt, n0,        0, sm + 16384 + 0 * 8192, tid);
    stage_half(Bt, n0 + 128,  0, sm + 16384 + 1 * 8192, tid);
    stage_half(Bt, n0,       64, sm + 16384 + 2 * 8192, tid);
    stage_half(Bt, n0 + 128, 64, sm + 16384 + 3 * 8192, tid);
    VMW4;
    __builtin_amdgcn_s_barrier();

    for (int i = 0; i < 15; i++) {
        const int k0 = i * 128;
        rd_b(As0, 0, 0, l16, quad, af); rd_b(Bs0, 0, sub, l16, quad, b0);
        stage_half64(A, m0, k0 + 64, sm + 2 * 4096, tid);
        MIDB; mm4<0, 0>(acc, af, b0); ENDB;
        rd_b(Bs0, 1, sub, l16, quad, b1);
        stage_half64(A, m0 + 64, k0 + 64, sm + 3 * 4096, tid);
        MIDB; mm4<0, 1>(acc, af, b1); ENDB;
        rd_b(As0, 1, 0, l16, quad, af);
        stage_half(Bt, n0, k0 + 128, sm + 16384 + 0 * 8192, tid);
        MIDB; mm4<1, 1>(acc, af, b1); ENDB;
        stage_half(Bt, n0 + 128, k0 + 128, sm + 16384 + 1 * 8192, tid);
        MIDB; mm4<1, 0>(acc, af, b0); VMW4; ENDB;
        rd_b(As1, 0, 0, l16, quad, af); rd_b(Bs1, 0, sub, l16, quad, b0);
        stage_half64(A, m0, k0 + 128, sm + 0 * 4096, tid);
        MIDB; mm4<0, 0>(acc, af, b0); ENDB;
        rd_b(Bs1, 1, sub, l16, quad, b1);
        stage_half64(A, m0 + 64, k0 + 128, sm + 1 * 4096, tid);
        MIDB; mm4<0, 1>(acc, af, b1); ENDB;
        rd_b(As1, 1, 0, l16, quad, af);
        stage_half(Bt, n0, k0 + 192, sm + 16384 + 2 * 8192, tid);
        MIDB; mm4<1, 1>(acc, af, b1); ENDB;
        stage_half(Bt, n0 + 128, k0 + 192, sm + 16384 + 3 * 8192, tid);
        MIDB; mm4<1, 0>(acc, af, b0); VMW4; ENDB;
    }
    {
        rd_b(As0, 0, 0, l16, quad, af); rd_b(Bs0, 0, sub, l16, quad, b0);
        stage_half64(A, m0, 1984, sm + 2 * 4096, tid);
        MIDB; mm4<0, 0>(acc, af, b0); ENDB;
        rd_b(Bs0, 1, sub, l16, quad, b1);
        stage_half64(A, m0 + 64, 1984, sm + 3 * 4096, tid);
        MIDB; mm4<0, 1>(acc, af, b1); ENDB;
        rd_b(As0, 1, 0, l16, quad, af);
        MIDB; mm4<1, 1>(acc, af, b1); ENDB;
        MIDB; mm4<1, 0>(acc, af, b0); VMW0; ENDB;
        rd_b(As1, 0, 0, l16, quad, af); rd_b(Bs1, 0, sub, l16, quad, b0);
        MIDB; mm4<0, 0>(acc, af, b0); ENDB;
        rd_b(Bs1, 1, sub, l16, quad, b1);
        MIDB; mm4<0, 1>(acc, af, b1); ENDB;
        rd_b(As1, 1, 0, l16, quad, af);
        MIDB; mm4<1, 1>(acc, af, b1); ENDB;
        MIDB; mm4<1, 0>(acc, af, b0); ENDB;
    }

#pragma unroll
    for (int am = 0; am < 4; am++)
#pragma unroll
        for (int an = 0; an < 4; an++)
#pragma unroll
            for (int r = 0; r < 4; r++) {
                int row = m0 + wr * 64 + am * 16 + quad * 4 + r;
                int col = n0 + wc * 64 + an * 16 + l16;
                C[(size_t)row * C_ + col] = acc[am][an][r];
            }
}

// ---------------- flash attention: round-3 structure, unroll-by-2 + SM/PV interleave ----------------
// 128 q/block (4 waves x 32 q), 64-key tiles, 2 blocks/CU, 64 KB static LDS:
//   Ks[2] @ u16 {0, 8192}; Vs[2] @ {16384, 24576}.
// kt-loop unrolled by 2 -> buffer slots are compile-time -> LDS addresses CSE'd.
// Per tile: issue K(t+1) gload_lds + V(t+1)->regs; QK; SM(ni0,1); PV(ks2=0);
// SM(ni2,3); PV(ks2=1)  [PV0 MFMAs overlap SM23 VALU - no dependence];
// vmcnt(0); V-write(t+1); barrier.
__global__ __launch_bounds__(256, 2) void k_attn(const u16* __restrict__ qa,
                                                 const u16* __restrict__ ka,
                                                 const u16* __restrict__ vt,
                                                 u16* __restrict__ ya) {
    __shared__ __align__(16) u16 smem[32768]; // 64 KB
    u16* const Ks0 = smem;
    u16* const Ks1 = smem + 8192;
    u16* const Vs0 = smem + 16384;
    u16* const Vs1 = smem + 24576;
    const int tid = threadIdx.x;
    const int wave = tid >> 6, lane = tid & 63;
    const int quad = lane >> 4, l16 = lane & 15;
    const int qt = blockIdx.x, h = blockIdx.y, b = blockIdx.z;
    const int g = h >> 2;

    bf16x8 qf[2][4];
    {
        const u16* qbase = qa + (((size_t)(b * NH + h)) * T_ + qt * 128 + wave * 32 + l16) * 128;
#pragma unroll
        for (int t16 = 0; t16 < 2; t16++)
#pragma unroll
            for (int ks = 0; ks < 4; ks++)
                qf[t16][ks] = *(const bf16x8*)(qbase + t16 * 16 * 128 + ks * 32 + quad * 8);
    }
    const u16* kbase = ka + ((size_t)(b * NG + g)) * T_ * 128;
    const u16* vbase = vt + ((size_t)(b * NG + g)) * 128 * T_;

    // hoisted per-thread staging offsets (loop-invariant)
    int kdst[4], ksrc[4], vsrc[4], vdA[4], vdB[4];
#pragma unroll
    for (int i = 0; i < 4; i++) {
        int c = tid + i * 256;
        int row = c >> 4, seg = c & 15;
        kdst[i] = c * 8;
        ksrc[i] = row * 128 + (seg ^ (row & 15)) * 8;
        int d = c >> 3, m = c & 7;
        vsrc[i] = d * T_ + m * 8;
        int segA = (m >> 2) * 4 + (m & 1) * 2;
        int a4 = ((m >> 1) & 1) * 4;
        vdA[i] = d * 64 + (segA ^ (d & 7)) * 8 + a4;
        vdB[i] = d * 64 + ((segA + 1) ^ (d & 7)) * 8 + a4;
    }

    f32x4 yacc[2][8] = {};
    float lsum[2] = {0.f, 0.f};
    uint4 vr[4];

    auto ISSUE_K = [&](int kt, u16* Kn) {
        const u16* kb = kbase + (size_t)kt * 8192;
#pragma unroll
        for (int i = 0; i < 4; i++)
            __builtin_amdgcn_global_load_lds(
                (const __attribute__((address_space(1))) void*)(kb + ksrc[i]),
                (__attribute__((address_space(3))) void*)(Kn + kdst[i]), 16, 0, 0);
    };
    auto LOAD_V = [&](int kt) {
        const u16* vb = vbase + kt * 64;
#pragma unroll
        for (int i = 0; i < 4; i++) vr[i] = *(const uint4*)(vb + vsrc[i]);
    };
    auto WRITE_V = [&](u16* Vc) {
#pragma unroll
        for (int i = 0; i < 4; i++) {
            *(uint2*)&Vc[vdA[i]] = make_uint2(vr[i].x, vr[i].y);
            *(uint2*)&Vc[vdB[i]] = make_uint2(vr[i].z, vr[i].w);
        }
    };

    // STEP: compute tile from (Kc,Vc); optionally stage tile kt1 into (Kn,Vn).
    auto STEP = [&](const u16* Kc, const u16* Vc, u16* Kn, u16* Vn, int kt1, bool stage) {
        if (stage) { ISSUE_K(kt1, Kn); LOAD_V(kt1); }

        // QK: S^T = K*Q^T
        f32x4 sacc[2][4];
#pragma unroll
        for (int t16 = 0; t16 < 2; t16++)
#pragma unroll
            for (int ni = 0; ni < 4; ni++) sacc[t16][ni] = f32x4{0.f, 0.f, 0.f, 0.f};
        __builtin_amdgcn_s_setprio(1);
#pragma unroll
        for (int ks = 0; ks < 4; ks++) {
#pragma unroll
            for (int ni = 0; ni < 4; ni++) {
                bf16x8 kf = *(const bf16x8*)&Kc[(ni * 16 + l16) * 128 + ((ks * 4 + quad) ^ l16) * 8];
                sacc[0][ni] = __builtin_amdgcn_mfma_f32_16x16x32_bf16(kf, qf[0][ks], sacc[0][ni], 0, 0, 0);
                sacc[1][ni] = __builtin_amdgcn_mfma_f32_16x16x32_bf16(kf, qf[1][ks], sacc[1][ni], 0, 0, 0);
            }
        }
        __builtin_amdgcn_s_setprio(0);

        uint32_t pk[2][4][2];
        // SM half h0: ni = h0*2, h0*2+1 ; PV half ks2 consumes pk[*][2*ks2..2*ks2+1]
#pragma unroll
        for (int h0 = 0; h0 < 2; h0++) {
#pragma unroll
            for (int t16 = 0; t16 < 2; t16++) {
#pragma unroll
                for (int nn = 0; nn < 2; nn++) {
                    const int ni = h0 * 2 + nn;
                    float p0 = fast_ex2(sacc[t16][ni][0]);
                    float p1 = fast_ex2(sacc[t16][ni][1]);
                    float p2 = fast_ex2(sacc[t16][ni][2]);
                    float p3 = fast_ex2(sacc[t16][ni][3]);
                    lsum[t16] += (p0 + p1) + (p2 + p3);
                    asm("v_cvt_pk_bf16_f32 %0, %1, %2" : "=v"(pk[t16][ni][0]) : "v"(p0), "v"(p1));
                    asm("v_cvt_pk_bf16_f32 %0, %1, %2" : "=v"(pk[t16][ni][1]) : "v"(p2), "v"(p3));
                }
            }
            // PV half: Y^T += V^T * P^T for ks2 = h0
            union { uint32_t u[4]; bf16x8 v; } pf0, pf1;
            pf0.u[0] = pk[0][2 * h0][0];     pf0.u[1] = pk[0][2 * h0][1];
            pf0.u[2] = pk[0][2 * h0 + 1][0]; pf0.u[3] = pk[0][2 * h0 + 1][1];
            pf1.u[0] = pk[1][2 * h0][0];     pf1.u[1] = pk[1][2 * h0][1];
            pf1.u[2] = pk[1][2 * h0 + 1][0]; pf1.u[3] = pk[1][2 * h0 + 1][1];
            __builtin_amdgcn_s_setprio(1);
#pragma unroll
            for (int tile = 0; tile < 8; tile++) {
                bf16x8 vf = *(const bf16x8*)&Vc[(tile * 16 + l16) * 64 +
                                                ((h0 * 4 + quad) ^ (l16 & 7)) * 8];
                yacc[0][tile] = __builtin_amdgcn_mfma_f32_16x16x32_bf16(vf, pf0.v, yacc[0][tile], 0, 0, 0);
                yacc[1][tile] = __builtin_amdgcn_mfma_f32_16x16x32_bf16(vf, pf1.v, yacc[1][tile], 0, 0, 0);
            }
            __builtin_amdgcn_s_setprio(0);
        }

        if (stage) {
            asm volatile("s_waitcnt vmcnt(0)" ::: "memory");
            WRITE_V(Vn);
        }
        __syncthreads();
    };

    // prologue: land K(0) -> Ks0, V(0) -> Vs0
    ISSUE_K(0, Ks0); LOAD_V(0);
    asm volatile("s_waitcnt vmcnt(0)" ::: "memory");
    WRITE_V(Vs0);
    __syncthreads();

    for (int kt = 0; kt < 30; kt += 2) {
        STEP(Ks0, Vs0, Ks1, Vs1, kt + 1, true);   // tile kt   (slot0), stage kt+1 -> slot1
        STEP(Ks1, Vs1, Ks0, Vs0, kt + 2, true);   // tile kt+1 (slot1), stage kt+2 -> slot0
    }
    STEP(Ks0, Vs0, Ks1, Vs1, 31, true);           // tile 30, stage 31 -> slot1
    STEP(Ks1, Vs1, nullptr, nullptr, 0, false);   // tile 31, no staging

    // reduce l across the 4 lane-replicas (lanes 16/32 apart hold same q)
#pragma unroll
    for (int t16 = 0; t16 < 2; t16++) {
        lsum[t16] += __shfl_xor(lsum[t16], 16);
        lsum[t16] += __shfl_xor(lsum[t16], 32);
    }

    // epilogue: Y^T[d][q] registers -> LDS [q][d] (swizzled) -> coalesced global
#pragma unroll
    for (int t16 = 0; t16 < 2; t16++) {
        float inv = 1.f / lsum[t16];
        int qrow = wave * 32 + t16 * 16 + l16;
#pragma unroll
        for (int tile = 0; tile < 8; tile++) {
#pragma unroll
            for (int cp = 0; cp < 2; cp++) {
                int d = tile * 16 + quad * 4 + cp * 2;
                uint32_t pv = (uint32_t)f2bf(yacc[t16][tile][cp * 2] * inv) |
                              ((uint32_t)f2bf(yacc[t16][tile][cp * 2 + 1] * inv) << 16);
                *(uint32_t*)&smem[qrow * 128 + ((d >> 3) ^ l16) * 8 + (d & 7)] = pv;
            }
        }
    }
    __syncthreads();
#pragma unroll
    for (int i = 0; i < 8; i++) {
        int cc = tid + i * 256;
        int row = cc >> 4, seg = cc & 15;
        uint4 dv = *(const uint4*)&smem[row * 128 + (seg ^ (row & 15)) * 8];
        size_t q = (size_t)(b * T_ + qt * 128 + row);
        *(uint4*)(ya + q * C_ + h * 128 + seg * 8) = dv;
    }
}

extern "C" void kernel_launch(void* const* d_in, const int* in_sizes, int n_in,
                              void* d_out, int out_size, void* d_ws, size_t ws_size,
                              hipStream_t stream) {
    (void)in_sizes; (void)n_in; (void)out_size; (void)ws_size;
    const float* x = (const float*)d_in[0];
    const float* cosb = (const float*)d_in[1];
    const float* sinb = (const float*)d_in[2];
    const float* w_attn = (const float*)d_in[3];
    const float* w_proj = (const float*)d_in[4];
    float* out = (float*)d_out;

    char* ws = (char*)d_ws;
    size_t off = 0;
    auto alloc = [&](size_t bytes) -> char* {
        char* p = ws + off;
        off += (bytes + 255) & ~(size_t)255;
        return p;
    };
    u16* xb  = (u16*)alloc((size_t)4096 * 2048 * 2);
    u16* wat = (u16*)alloc((size_t)3072 * 2048 * 2);
    u16* wpt = (u16*)alloc((size_t)2048 * 2048 * 2);
    u16* qa  = (u16*)alloc((size_t)B_ * NH * T_ * HS * 2);
    u16* ka  = (u16*)alloc((size_t)B_ * NG * T_ * HS * 2);
    u16* vt  = (u16*)alloc((size_t)B_ * NG * T_ * HS * 2);
    u16* ya  = xb; // xb dead after gemm1

    static bool smset = false;
    if (!smset) {
        (void)hipFuncSetAttribute((const void*)k_gemm_qkv,
                                  hipFuncAttributeMaxDynamicSharedMemorySize, 131072);
        (void)hipFuncSetAttribute((const void*)k_gemm_bt,
                                  hipFuncAttributeMaxDynamicSharedMemorySize, 98304);
        smset = true;
    }

    k_prep<<<dim3(18432), dim3(256), 0, stream>>>(x, xb, w_attn, wat, w_proj, wpt);
    k_gemm_qkv<<<dim3(12, 16), dim3(512), 131072, stream>>>(xb, wat, cosb, sinb, qa, ka, vt);
    k_attn<<<dim3(16, 16, 2), dim3(256), 0, stream>>>(qa, ka, vt, ya);
    k_gemm_bt<<<dim3(8, 32), dim3(512), 98304, stream>>>(ya, wpt, out);
}